// Round 1
// baseline (6165.138 us; speedup 1.0000x reference)
//
#include <hip/hip_runtime.h>
#include <cmath>

// CustomRNNCell: h_{t+1} = tanh(h_t @ W_h^T + b_h + x_t @ W_x^T + b_x)
// B=64, T=512, H=I=1024. Output: h_final [64,1024] fp32.
//
// Phase 1: xp[t][b][j] = x @ W_x^T + (b_x + b_h)   (bf16 MFMA GEMM, fp32 out)
// Phase 2: persistent scan kernel, W_h bf16 resident in LDS,
//          128 blocks = 4 batch-groups x 32 col-groups, per-group spin barrier.

#define Bsz 64
#define Tsz 512
#define Hsz 1024

typedef float  f32x4 __attribute__((ext_vector_type(4)));
typedef short  s16x8 __attribute__((ext_vector_type(8)));

__device__ __forceinline__ unsigned short f2bf(float f) {
  unsigned u = __float_as_uint(f);
  u += 0x7fff + ((u >> 16) & 1);   // round-to-nearest-even (finite inputs)
  return (unsigned short)(u >> 16);
}

__device__ __forceinline__ void pack8(unsigned short* d, float4 v0, float4 v1) {
  d[0] = f2bf(v0.x); d[1] = f2bf(v0.y); d[2] = f2bf(v0.z); d[3] = f2bf(v0.w);
  d[4] = f2bf(v1.x); d[5] = f2bf(v1.y); d[6] = f2bf(v1.z); d[7] = f2bf(v1.w);
}

// ---------------- Phase 1: xp GEMM ----------------
// grid (512,16), block 256 (4 waves). Tile M=64,N=64,K-step 32.
// Wave w owns rows w*16..w*16+15 of the tile, all 64 cols (4 n-tiles).
__global__ __launch_bounds__(256) void xp_gemm_kernel(
    const float* __restrict__ x, const float* __restrict__ Wx,
    const float* __restrict__ bx, const float* __restrict__ bh,
    float* __restrict__ xp) {
  __shared__ unsigned short Al[64 * 32];  // 4 KB, bf16, XOR-swizzled chunks
  __shared__ unsigned short Bl[64 * 32];

  const int tid  = threadIdx.x;
  const int w    = tid >> 6;
  const int lane = tid & 63;
  const int m    = lane & 15;
  const int q    = lane >> 4;
  const int row0 = blockIdx.x * 64;   // flattened (b*T + t) row base
  const int col0 = blockIdx.y * 64;   // hidden col base

  f32x4 acc[4];
#pragma unroll
  for (int i = 0; i < 4; ++i) acc[i] = (f32x4){0.f, 0.f, 0.f, 0.f};

  const int sr = tid >> 2;                  // staging row 0..63
  const int sc = tid & 3;                   // chunk (8 floats) 0..3
  const int sw = sc ^ ((sr >> 1) & 3);      // swizzled chunk

  for (int kt = 0; kt < 32; ++kt) {
    const int k0 = kt * 32 + sc * 8;
    {
      const float* p = x + (size_t)(row0 + sr) * 1024 + k0;
      pack8(&Al[sr * 32 + sw * 8], *(const float4*)p, *(const float4*)(p + 4));
    }
    {
      const float* p = Wx + (size_t)(col0 + sr) * 1024 + k0;
      pack8(&Bl[sr * 32 + sw * 8], *(const float4*)p, *(const float4*)(p + 4));
    }
    __syncthreads();
    const int arow = w * 16 + m;
    s16x8 a = *(const s16x8*)&Al[arow * 32 + ((q ^ ((arow >> 1) & 3)) << 3)];
#pragma unroll
    for (int nt = 0; nt < 4; ++nt) {
      const int nrow = nt * 16 + m;
      s16x8 b = *(const s16x8*)&Bl[nrow * 32 + ((q ^ ((nrow >> 1) & 3)) << 3)];
      acc[nt] = __builtin_amdgcn_mfma_f32_16x16x32_bf16(a, b, acc[nt], 0, 0, 0);
    }
    __syncthreads();
  }

  // epilogue: +b_x+b_h, write xp in [T][B][H] layout
#pragma unroll
  for (int nt = 0; nt < 4; ++nt) {
    const int col  = col0 + nt * 16 + m;
    const float bias = bx[col] + bh[col];
#pragma unroll
    for (int r = 0; r < 4; ++r) {
      const int rowg = row0 + w * 16 + q * 4 + r;  // = b*512 + t
      const int b = rowg >> 9;
      const int t = rowg & 511;
      xp[(size_t)t * (Bsz * Hsz) + b * Hsz + col] = acc[nt][r] + bias;
    }
  }
}

// ---------------- Phase 2: persistent scan ----------------
// 128 blocks x 128 threads (2 waves). Block (gb,gj): rows gb*16..+15,
// cols gj*32..+31 (wave w -> 16 cols). W_h slice 32x1024 bf16 in LDS (64 KB).
__global__ __launch_bounds__(128) void rnn_scan_kernel(
    const float* __restrict__ Wh, const float* __restrict__ xp,
    float* __restrict__ out, unsigned short* __restrict__ h0buf,
    unsigned short* __restrict__ h1buf, unsigned* __restrict__ bars) {
  __shared__ unsigned short Wl[32 * 1024];  // 64 KB

  const int tid  = threadIdx.x;
  const int w    = tid >> 6;
  const int lane = tid & 63;
  const int m    = lane & 15;
  const int q    = lane >> 4;
  const int gb   = blockIdx.x >> 5;   // 0..3  batch group
  const int gj   = blockIdx.x & 31;   // 0..31 col group
  const int rb   = gb * 16;
  const int j0   = gj * 32;

  // W_h rows j0..j0+31 -> LDS bf16, chunk-swizzled (chunk ^= row&7)
  for (int jr = 0; jr < 32; ++jr) {
    const int k0 = tid * 8;           // 128 threads x 8 = 1024
    const float* p = Wh + (size_t)(j0 + jr) * 1024 + k0;
    unsigned short* d = &Wl[jr * 1024 + ((((unsigned)tid) ^ (jr & 7)) << 3)];
    pack8(d, *(const float4*)p, *(const float4*)(p + 4));
  }
  __syncthreads();

  const int colg = j0 + w * 16 + m;   // output col this lane produces
  const int jl   = w * 16 + m;        // local W row (B-operand col)
  unsigned* cnt = bars + gb * 64;     // 256-B separated per group
  unsigned* gen = bars + gb * 64 + 32;
  unsigned my_gen = 0;

  for (int t = 0; t < Tsz; ++t) {
    const unsigned short* hc = (t & 1) ? h1buf : h0buf;
    unsigned short*       hn = (t & 1) ? h0buf : h1buf;

    // prefetch xp_t (needed only after the k-loop)
    float xv[4];
#pragma unroll
    for (int r = 0; r < 4; ++r)
      xv[r] = xp[(size_t)t * (Bsz * Hsz) + (rb + q * 4 + r) * Hsz + colg];

    f32x4 acc0 = (f32x4){0.f, 0.f, 0.f, 0.f};
    f32x4 acc1 = (f32x4){0.f, 0.f, 0.f, 0.f};
#pragma unroll 4
    for (int kt = 0; kt < 32; kt += 2) {
      s16x8 a0 = *(const s16x8*)(hc + ((rb + m) << 10) + kt * 32 + q * 8);
      s16x8 b0 = *(const s16x8*)&Wl[jl * 1024 + (((kt * 4 + q) ^ (jl & 7)) << 3)];
      acc0 = __builtin_amdgcn_mfma_f32_16x16x32_bf16(a0, b0, acc0, 0, 0, 0);
      s16x8 a1 = *(const s16x8*)(hc + ((rb + m) << 10) + (kt + 1) * 32 + q * 8);
      s16x8 b1 = *(const s16x8*)&Wl[jl * 1024 + ((((kt + 1) * 4 + q) ^ (jl & 7)) << 3)];
      acc1 = __builtin_amdgcn_mfma_f32_16x16x32_bf16(a1, b1, acc1, 0, 0, 0);
    }
    f32x4 acc = acc0 + acc1;

#pragma unroll
    for (int r = 0; r < 4; ++r) {
      const float hv = tanhf(acc[r] + xv[r]);
      const int rowg = rb + q * 4 + r;
      hn[rowg * Hsz + colg] = f2bf(hv);
      if (t == Tsz - 1) out[rowg * Hsz + colg] = hv;
    }

    // per-group barrier (32 blocks), sense via monotone generation counter
    __syncthreads();
    if (tid == 0) {
      __threadfence();  // make h writes visible device-wide
      ++my_gen;
      unsigned arrived =
          __hip_atomic_fetch_add(cnt, 1u, __ATOMIC_ACQ_REL, __HIP_MEMORY_SCOPE_AGENT);
      if (arrived == 31u) {
        __hip_atomic_store(cnt, 0u, __ATOMIC_RELAXED, __HIP_MEMORY_SCOPE_AGENT);
        __hip_atomic_fetch_add(gen, 1u, __ATOMIC_RELEASE, __HIP_MEMORY_SCOPE_AGENT);
      } else {
        while (__hip_atomic_load(gen, __ATOMIC_ACQUIRE, __HIP_MEMORY_SCOPE_AGENT) < my_gen) {
          __builtin_amdgcn_s_sleep(1);
        }
      }
    }
    __syncthreads();
  }
}

extern "C" void kernel_launch(void* const* d_in, const int* in_sizes, int n_in,
                              void* d_out, int out_size, void* d_ws, size_t ws_size,
                              hipStream_t stream) {
  (void)in_sizes; (void)n_in; (void)out_size; (void)ws_size;
  const float* x  = (const float*)d_in[0];  // [64,512,1024]
  const float* Wh = (const float*)d_in[1];  // [1024,1024]
  const float* bh = (const float*)d_in[2];  // [1024]
  const float* Wx = (const float*)d_in[3];  // [1024,1024]
  const float* bx = (const float*)d_in[4];  // [1024]
  float* out = (float*)d_out;               // [64,1024]

  char* ws = (char*)d_ws;
  unsigned*       bars = (unsigned*)ws;                       // 1 KB used
  unsigned short* h0   = (unsigned short*)(ws + 4096);        // 128 KB
  unsigned short* h1   = (unsigned short*)(ws + 4096 + 131072);
  float*          xp   = (float*)(ws + (1 << 20));            // 128 MB

  // zero barrier counters + h ping-pong buffers (ws is poisoned each call)
  hipMemsetAsync(d_ws, 0, 1 << 20, stream);

  dim3 g1(Bsz * Tsz / 64, Hsz / 64);
  xp_gemm_kernel<<<g1, dim3(256), 0, stream>>>(x, Wx, bx, bh, xp);
  rnn_scan_kernel<<<dim3(128), dim3(128), 0, stream>>>(Wh, xp, out, h0, h1, bars);
}

// Round 2
// 3247.226 us; speedup vs baseline: 1.8986x; 1.8986x over previous
//
#include <hip/hip_runtime.h>
#include <cmath>

// CustomRNNCell: h_{t+1} = tanh(h_t @ W_h^T + b_h + x_t @ W_x^T + b_x)
// B=64, T=512, H=I=1024. Output: h_final [64,1024] fp32.
//
// Phase 1: xp[t][b][j] = x @ W_x^T + (b_x + b_h)   (bf16 MFMA GEMM, fp32 out)
// Phase 2: persistent scan, W_h bf16 resident in LDS (32 cols/block),
//          128 blocks = 4 batch-groups x 32 col-groups.
//          h exchanged via L2-BYPASSING relaxed agent atomics (sc0/sc1) --
//          no fences, no L2 writeback/invalidate. Sync = distributed flags,
//          polled in parallel (one flag per lane + ballot).

#define Bsz 64
#define Tsz 512
#define Hsz 1024

typedef float  f32x4 __attribute__((ext_vector_type(4)));
typedef short  s16x8 __attribute__((ext_vector_type(8)));

__device__ __forceinline__ unsigned short f2bf(float f) {
  unsigned u = __float_as_uint(f);
  u += 0x7fff + ((u >> 16) & 1);   // round-to-nearest-even (finite inputs)
  return (unsigned short)(u >> 16);
}

__device__ __forceinline__ void pack8(unsigned short* d, float4 v0, float4 v1) {
  d[0] = f2bf(v0.x); d[1] = f2bf(v0.y); d[2] = f2bf(v0.z); d[3] = f2bf(v0.w);
  d[4] = f2bf(v1.x); d[5] = f2bf(v1.y); d[6] = f2bf(v1.z); d[7] = f2bf(v1.w);
}

// ---------------- Phase 1: xp GEMM (unchanged from R1) ----------------
__global__ __launch_bounds__(256) void xp_gemm_kernel(
    const float* __restrict__ x, const float* __restrict__ Wx,
    const float* __restrict__ bx, const float* __restrict__ bh,
    float* __restrict__ xp) {
  __shared__ unsigned short Al[64 * 32];
  __shared__ unsigned short Bl[64 * 32];

  const int tid  = threadIdx.x;
  const int w    = tid >> 6;
  const int lane = tid & 63;
  const int m    = lane & 15;
  const int q    = lane >> 4;
  const int row0 = blockIdx.x * 64;   // flattened (b*T + t) row base
  const int col0 = blockIdx.y * 64;   // hidden col base

  f32x4 acc[4];
#pragma unroll
  for (int i = 0; i < 4; ++i) acc[i] = (f32x4){0.f, 0.f, 0.f, 0.f};

  const int sr = tid >> 2;
  const int sc = tid & 3;
  const int sw = sc ^ ((sr >> 1) & 3);

  for (int kt = 0; kt < 32; ++kt) {
    const int k0 = kt * 32 + sc * 8;
    {
      const float* p = x + (size_t)(row0 + sr) * 1024 + k0;
      pack8(&Al[sr * 32 + sw * 8], *(const float4*)p, *(const float4*)(p + 4));
    }
    {
      const float* p = Wx + (size_t)(col0 + sr) * 1024 + k0;
      pack8(&Bl[sr * 32 + sw * 8], *(const float4*)p, *(const float4*)(p + 4));
    }
    __syncthreads();
    const int arow = w * 16 + m;
    s16x8 a = *(const s16x8*)&Al[arow * 32 + ((q ^ ((arow >> 1) & 3)) << 3)];
#pragma unroll
    for (int nt = 0; nt < 4; ++nt) {
      const int nrow = nt * 16 + m;
      s16x8 b = *(const s16x8*)&Bl[nrow * 32 + ((q ^ ((nrow >> 1) & 3)) << 3)];
      acc[nt] = __builtin_amdgcn_mfma_f32_16x16x32_bf16(a, b, acc[nt], 0, 0, 0);
    }
    __syncthreads();
  }

#pragma unroll
  for (int nt = 0; nt < 4; ++nt) {
    const int col  = col0 + nt * 16 + m;
    const float bias = bx[col] + bh[col];
#pragma unroll
    for (int r = 0; r < 4; ++r) {
      const int rowg = row0 + w * 16 + q * 4 + r;  // = b*512 + t
      const int b = rowg >> 9;
      const int t = rowg & 511;
      xp[(size_t)t * (Bsz * Hsz) + b * Hsz + col] = acc[nt][r] + bias;
    }
  }
}

// ---------------- Phase 2: persistent scan, fence-free ----------------
// 128 blocks x 128 threads (2 waves). Block (gb,gj): rows gb*16..+15,
// cols gj*32..+31 (wave w -> 16 cols). W_h slice 32x1024 bf16 in LDS (64 KB).
__global__ __launch_bounds__(128) void rnn_scan_kernel(
    const float* __restrict__ Wh, const float* __restrict__ xp,
    float* __restrict__ out,
    unsigned short* __restrict__ h0buf, unsigned short* __restrict__ h1buf,
    unsigned* __restrict__ flags) {
  __shared__ unsigned short Wl[32 * 1024];  // 64 KB

  const int tid  = threadIdx.x;
  const int w    = tid >> 6;
  const int lane = tid & 63;
  const int m    = lane & 15;
  const int q    = lane >> 4;
  const int gb   = blockIdx.x >> 5;   // 0..3  batch group
  const int gj   = blockIdx.x & 31;   // 0..31 col group
  const int rb   = gb * 16;
  const int j0   = gj * 32;

  // W_h rows j0..j0+31 -> LDS bf16, chunk-swizzled (chunk ^= row&7)
  for (int jr = 0; jr < 32; ++jr) {
    const int k0 = tid * 8;           // 128 threads x 8 = 1024
    const float* p = Wh + (size_t)(j0 + jr) * 1024 + k0;
    unsigned short* d = &Wl[jr * 1024 + ((((unsigned)tid) ^ (jr & 7)) << 3)];
    pack8(d, *(const float4*)p, *(const float4*)(p + 4));
  }
  __syncthreads();

  const int colg = j0 + w * 16 + m;   // output col this lane produces
  const int jl   = w * 16 + m;        // local W row (B-operand col)

  // flags: one 64-B-strided slot per (gb,gj); value = #steps completed
  unsigned* grpflags = flags + gb * 32 * 16;
  unsigned* myflag   = grpflags + gj * 16;
  const unsigned* pollflag = grpflags + (lane & 31) * 16;

  for (int t = 0; t < Tsz; ++t) {
    const unsigned short* hc = (t & 1) ? h1buf : h0buf;
    unsigned short*       hn = (t & 1) ? h0buf : h1buf;

    // xp_t loads issued BEFORE the poll -- latency hides behind the wait
    float xv[4];
#pragma unroll
    for (int r = 0; r < 4; ++r)
      xv[r] = xp[(size_t)t * (Bsz * Hsz) + (rb + q * 4 + r) * Hsz + colg];

    f32x4 acc0 = (f32x4){0.f, 0.f, 0.f, 0.f};
    f32x4 acc1 = (f32x4){0.f, 0.f, 0.f, 0.f};

    if (t > 0) {
      // parallel poll: lane L watches flag of group-block (L&31)
      for (;;) {
        unsigned v = __hip_atomic_load(pollflag, __ATOMIC_RELAXED,
                                       __HIP_MEMORY_SCOPE_AGENT);
        if (__ballot(v >= (unsigned)t) == ~0ull) break;
        __builtin_amdgcn_s_sleep(1);
      }

      // A-fragment loads: L2-bypassing 8-B atomic loads (coherent, no inv)
      const unsigned long long* hrow =
          (const unsigned long long*)(hc + ((rb + m) << 10));
#pragma unroll 4
      for (int kt = 0; kt < 32; kt += 2) {
        const int c0 = kt * 4 + q;          // 16-B chunk index 0..127
        const int c1 = (kt + 1) * 4 + q;
        union { unsigned long long u[2]; s16x8 v; } a0, a1;
        a0.u[0] = __hip_atomic_load(hrow + c0 * 2,     __ATOMIC_RELAXED, __HIP_MEMORY_SCOPE_AGENT);
        a0.u[1] = __hip_atomic_load(hrow + c0 * 2 + 1, __ATOMIC_RELAXED, __HIP_MEMORY_SCOPE_AGENT);
        a1.u[0] = __hip_atomic_load(hrow + c1 * 2,     __ATOMIC_RELAXED, __HIP_MEMORY_SCOPE_AGENT);
        a1.u[1] = __hip_atomic_load(hrow + c1 * 2 + 1, __ATOMIC_RELAXED, __HIP_MEMORY_SCOPE_AGENT);
        s16x8 b0 = *(const s16x8*)&Wl[jl * 1024 + ((c0 ^ (jl & 7)) << 3)];
        s16x8 b1 = *(const s16x8*)&Wl[jl * 1024 + ((c1 ^ (jl & 7)) << 3)];
        acc0 = __builtin_amdgcn_mfma_f32_16x16x32_bf16(a0.v, b0, acc0, 0, 0, 0);
        acc1 = __builtin_amdgcn_mfma_f32_16x16x32_bf16(a1.v, b1, acc1, 0, 0, 0);
      }
    }
    f32x4 acc = acc0 + acc1;

    float hv[4];
    unsigned hb[4];
#pragma unroll
    for (int r = 0; r < 4; ++r) {
      hv[r] = tanhf(acc[r] + xv[r]);
      hb[r] = f2bf(hv[r]);
    }

    if (t == Tsz - 1) {
      // final: write fp32 output (normal stores; kernel-end release flushes)
#pragma unroll
      for (int r = 0; r < 4; ++r)
        out[(rb + q * 4 + r) * Hsz + colg] = hv[r];
    } else {
      // pack column pairs (via shfl) -> 4-B coherent stores, 2 per lane
      const int odd = lane & 1;
#pragma unroll
      for (int r = 0; r < 4; ++r) {
        unsigned part = (unsigned)__shfl_xor((int)hb[r], 1, 64) & 0xffffu;
        unsigned word = odd ? (part | (hb[r] << 16)) : (hb[r] | (part << 16));
        if ((r >> 1) == odd) {   // even lane stores rows 0,1; odd rows 2,3
          unsigned* dst = (unsigned*)(hn + (rb + q * 4 + r) * Hsz + (colg & ~1));
          __hip_atomic_store(dst, word, __ATOMIC_RELAXED, __HIP_MEMORY_SCOPE_AGENT);
        }
      }
    }

    // barrier drains vmcnt per wave (compiler emits s_waitcnt vmcnt(0) before
    // s_barrier) => all write-through h stores are at the coherence point.
    __syncthreads();
    if (tid == 0 && t < Tsz - 1)
      __hip_atomic_store(myflag, (unsigned)(t + 1), __ATOMIC_RELAXED,
                         __HIP_MEMORY_SCOPE_AGENT);
  }
}

extern "C" void kernel_launch(void* const* d_in, const int* in_sizes, int n_in,
                              void* d_out, int out_size, void* d_ws, size_t ws_size,
                              hipStream_t stream) {
  (void)in_sizes; (void)n_in; (void)out_size; (void)ws_size;
  const float* x  = (const float*)d_in[0];  // [64,512,1024]
  const float* Wh = (const float*)d_in[1];  // [1024,1024]
  const float* bh = (const float*)d_in[2];  // [1024]
  const float* Wx = (const float*)d_in[3];  // [1024,1024]
  const float* bx = (const float*)d_in[4];  // [1024]
  float* out = (float*)d_out;               // [64,1024]

  char* ws = (char*)d_ws;
  unsigned*       flags = (unsigned*)ws;                      // 8 KB used
  unsigned short* h0    = (unsigned short*)(ws + 65536);      // 128 KB
  unsigned short* h1    = (unsigned short*)(ws + 65536 + 131072);
  float*          xp    = (float*)(ws + (1 << 20));           // 128 MB

  // only flags need zeroing (step 0 reads no h buffer)
  hipMemsetAsync(d_ws, 0, 16384, stream);

  dim3 g1(Bsz * Tsz / 64, Hsz / 64);
  xp_gemm_kernel<<<g1, dim3(256), 0, stream>>>(x, Wx, bx, bh, xp);
  rnn_scan_kernel<<<dim3(128), dim3(128), 0, stream>>>(Wh, xp, out, h0, h1, flags);
}

// Round 4
// 1827.802 us; speedup vs baseline: 3.3730x; 1.7766x over previous
//
#include <hip/hip_runtime.h>
#include <cmath>

// CustomRNNCell: h_{t+1} = tanh(h_t @ W_h^T + b_h + x_t @ W_x^T + b_x)
// B=64, T=512, H=I=1024. Output: h_final [64,1024] fp32.
//
// Phase 1: xp[t][b][j] = x @ W_x^T + (b_x + b_h)   (bf16 MFMA GEMM, fp32 out)
// Phase 2: persistent scan, W_h bf16 in LDS (32 cols/block),
//          128 blocks = 4 batch-groups x 32 col-groups.
//   R3: fragment-major h exchange + chunk-level pipelined flags.
//   R4: FIX — compiler memory fences around the LDS transpose read. The u64
//       readback of u16-written LDS was being reordered/hoisted by alias
//       analysis (read address is loop-invariant), yielding garbage h.

#define Bsz 64
#define Tsz 512
#define Hsz 1024

typedef float  f32x4 __attribute__((ext_vector_type(4)));
typedef short  s16x8 __attribute__((ext_vector_type(8)));

__device__ __forceinline__ unsigned short f2bf(float f) {
  unsigned u = __float_as_uint(f);
  u += 0x7fff + ((u >> 16) & 1);   // round-to-nearest-even (finite inputs)
  return (unsigned short)(u >> 16);
}

__device__ __forceinline__ void pack8(unsigned short* d, float4 v0, float4 v1) {
  d[0] = f2bf(v0.x); d[1] = f2bf(v0.y); d[2] = f2bf(v0.z); d[3] = f2bf(v0.w);
  d[4] = f2bf(v1.x); d[5] = f2bf(v1.y); d[6] = f2bf(v1.z); d[7] = f2bf(v1.w);
}

__device__ __forceinline__ float fast_tanh(float x) {
  // tanh(x) = 1 - 2/(exp(2x)+1); exp->inf/0 saturates to +-1 cleanly
  float e = __expf(2.0f * x);
  return 1.0f - 2.0f / (e + 1.0f);
}

// ---------------- Phase 1: xp GEMM (unchanged, validated) ----------------
__global__ __launch_bounds__(256) void xp_gemm_kernel(
    const float* __restrict__ x, const float* __restrict__ Wx,
    const float* __restrict__ bx, const float* __restrict__ bh,
    float* __restrict__ xp) {
  __shared__ unsigned short Al[64 * 32];
  __shared__ unsigned short Bl[64 * 32];

  const int tid  = threadIdx.x;
  const int w    = tid >> 6;
  const int lane = tid & 63;
  const int m    = lane & 15;
  const int q    = lane >> 4;
  const int row0 = blockIdx.x * 64;   // flattened (b*T + t) row base
  const int col0 = blockIdx.y * 64;   // hidden col base

  f32x4 acc[4];
#pragma unroll
  for (int i = 0; i < 4; ++i) acc[i] = (f32x4){0.f, 0.f, 0.f, 0.f};

  const int sr = tid >> 2;
  const int sc = tid & 3;
  const int sw = sc ^ ((sr >> 1) & 3);

  for (int kt = 0; kt < 32; ++kt) {
    const int k0 = kt * 32 + sc * 8;
    {
      const float* p = x + (size_t)(row0 + sr) * 1024 + k0;
      pack8(&Al[sr * 32 + sw * 8], *(const float4*)p, *(const float4*)(p + 4));
    }
    {
      const float* p = Wx + (size_t)(col0 + sr) * 1024 + k0;
      pack8(&Bl[sr * 32 + sw * 8], *(const float4*)p, *(const float4*)(p + 4));
    }
    __syncthreads();
    const int arow = w * 16 + m;
    s16x8 a = *(const s16x8*)&Al[arow * 32 + ((q ^ ((arow >> 1) & 3)) << 3)];
#pragma unroll
    for (int nt = 0; nt < 4; ++nt) {
      const int nrow = nt * 16 + m;
      s16x8 b = *(const s16x8*)&Bl[nrow * 32 + ((q ^ ((nrow >> 1) & 3)) << 3)];
      acc[nt] = __builtin_amdgcn_mfma_f32_16x16x32_bf16(a, b, acc[nt], 0, 0, 0);
    }
    __syncthreads();
  }

#pragma unroll
  for (int nt = 0; nt < 4; ++nt) {
    const int col  = col0 + nt * 16 + m;
    const float bias = bx[col] + bh[col];
#pragma unroll
    for (int r = 0; r < 4; ++r) {
      const int rowg = row0 + w * 16 + q * 4 + r;  // = b*512 + t
      const int b = rowg >> 9;
      const int t = rowg & 511;
      xp[(size_t)t * (Bsz * Hsz) + b * Hsz + col] = acc[nt][r] + bias;
    }
  }
}

// ---------------- Phase 2: pipelined persistent scan ----------------
// h buffers: per group (gb) 16384 bf16 elems, laid out as 32 producer-chunks
// of 512 elems; chunk kt = [q(4)][m(16)][8] with col = kt*32 + q*8 + j.
__global__ __launch_bounds__(128) void rnn_scan_kernel(
    const float* __restrict__ Wh, const float* __restrict__ xp,
    float* __restrict__ out,
    unsigned short* __restrict__ h0buf, unsigned short* __restrict__ h1buf,
    unsigned* __restrict__ flags) {
  __shared__ unsigned short Wl[32 * 1024];  // 64 KB
  __shared__ unsigned short Tr[2][16 * 20]; // per-wave transpose scratch (padded)

  const int tid  = threadIdx.x;
  const int w    = tid >> 6;
  const int lane = tid & 63;
  const int m    = lane & 15;
  const int q    = lane >> 4;
  const int gb   = blockIdx.x >> 5;   // 0..3  batch group
  const int gj   = blockIdx.x & 31;   // 0..31 col group (== producer chunk id)
  const int rb   = gb * 16;
  const int j0   = gj * 32;

  // W_h rows j0..j0+31 -> LDS bf16, chunk-swizzled (chunk ^= row&7)
  for (int jr = 0; jr < 32; ++jr) {
    const float* p = Wh + (size_t)(j0 + jr) * 1024 + tid * 8;
    unsigned short* d = &Wl[jr * 1024 + ((((unsigned)tid) ^ (jr & 7)) << 3)];
    pack8(d, *(const float4*)p, *(const float4*)(p + 4));
  }
  __syncthreads();

  const int colg = j0 + w * 16 + m;   // output col this lane produces
  const int jl   = w * 16 + m;        // local W row (B-operand col)

  unsigned* grpflags = flags + gb * 32 * 16;   // 64-B strided slots
  unsigned* myflag   = grpflags + gj * 16;
  const unsigned* pollflag = grpflags + (lane & 31) * 16;

  // transpose read indices (constant per lane)
  const int t_br = (lane >> 1) & 15;
  const int t_c0 = (lane >> 5) * 8 + (lane & 1) * 4;

  for (int t = 0; t < Tsz; ++t) {
    const unsigned short* hc = (t & 1) ? h1buf : h0buf;
    unsigned short*       hn = (t & 1) ? h0buf : h1buf;

    // xp_t loads (independent; hide behind polling / chunk loads)
    float xv[4];
#pragma unroll
    for (int r = 0; r < 4; ++r)
      xv[r] = xp[(size_t)t * (Bsz * Hsz) + (rb + q * 4 + r) * Hsz + colg];

    f32x4 acc0 = (f32x4){0.f, 0.f, 0.f, 0.f};
    f32x4 acc1 = (f32x4){0.f, 0.f, 0.f, 0.f};

    if (t > 0) {
      const unsigned long long* src =
          (const unsigned long long*)(hc + gb * 16384);
      const int loff = (q * 16 + m) * 2;   // u64 offset within a 128-u64 chunk

      // watermark = count of leading-ready chunks (flags polled in parallel)
      unsigned v = __hip_atomic_load(pollflag, __ATOMIC_RELAXED,
                                     __HIP_MEMORY_SCOPE_AGENT);
      int wm = (int)__builtin_ctzll(~__ballot(v >= (unsigned)t) |
                                    0xFFFFFFFF00000000ull);
#pragma unroll
      for (int g = 0; g < 4; ++g) {
        while (wm < (g + 1) * 8) {
          __builtin_amdgcn_s_sleep(1);
          unsigned v2 = __hip_atomic_load(pollflag, __ATOMIC_RELAXED,
                                          __HIP_MEMORY_SCOPE_AGENT);
          wm = (int)__builtin_ctzll(~__ballot(v2 >= (unsigned)t) |
                                    0xFFFFFFFF00000000ull);
        }
        union { unsigned long long u[2]; s16x8 v; } a[8];
#pragma unroll
        for (int j = 0; j < 8; ++j) {
          const unsigned long long* cp = src + (g * 8 + j) * 128 + loff;
          a[j].u[0] = __hip_atomic_load(cp,     __ATOMIC_RELAXED, __HIP_MEMORY_SCOPE_AGENT);
          a[j].u[1] = __hip_atomic_load(cp + 1, __ATOMIC_RELAXED, __HIP_MEMORY_SCOPE_AGENT);
        }
#pragma unroll
        for (int j = 0; j < 8; ++j) {
          const int c = (g * 8 + j) * 4 + q;
          s16x8 b = *(const s16x8*)&Wl[jl * 1024 + ((c ^ (jl & 7)) << 3)];
          if (j & 1)
            acc1 = __builtin_amdgcn_mfma_f32_16x16x32_bf16(a[j].v, b, acc1, 0, 0, 0);
          else
            acc0 = __builtin_amdgcn_mfma_f32_16x16x32_bf16(a[j].v, b, acc0, 0, 0, 0);
        }
      }
    }
    f32x4 acc = acc0 + acc1;

    float hv[4];
#pragma unroll
    for (int r = 0; r < 4; ++r) hv[r] = fast_tanh(acc[r] + xv[r]);

    if (t == Tsz - 1) {
#pragma unroll
      for (int r = 0; r < 4; ++r)
        out[(rb + q * 4 + r) * Hsz + colg] = hv[r];
    } else {
      // per-wave 16x16 transpose: C-layout (col=m, rows q*4+r) -> A-frag-major.
      // DS ops within a wave execute in order; the fences below stop the
      // COMPILER from hoisting/reordering the u64 readback (R3 bug).
      unsigned short* S = &Tr[w][0];
#pragma unroll
      for (int r = 0; r < 4; ++r)
        S[(q * 4 + r) * 20 + m] = f2bf(hv[r]);
      __asm__ __volatile__("" ::: "memory");
      unsigned long long tv =
          *(const volatile unsigned long long*)&S[t_br * 20 + t_c0];
      __asm__ __volatile__("" ::: "memory");
      unsigned long long* dst =
          (unsigned long long*)(hn + gb * 16384 + gj * 512 + w * 256) + lane;
      __hip_atomic_store(dst, tv, __ATOMIC_RELAXED, __HIP_MEMORY_SCOPE_AGENT);

      // drain stores (barrier forces vmcnt(0) for both waves), then flag
      __syncthreads();
      if (tid == 0)
        __hip_atomic_store(myflag, (unsigned)(t + 1), __ATOMIC_RELAXED,
                           __HIP_MEMORY_SCOPE_AGENT);
    }
  }
}

extern "C" void kernel_launch(void* const* d_in, const int* in_sizes, int n_in,
                              void* d_out, int out_size, void* d_ws, size_t ws_size,
                              hipStream_t stream) {
  (void)in_sizes; (void)n_in; (void)out_size; (void)ws_size;
  const float* x  = (const float*)d_in[0];  // [64,512,1024]
  const float* Wh = (const float*)d_in[1];  // [1024,1024]
  const float* bh = (const float*)d_in[2];  // [1024]
  const float* Wx = (const float*)d_in[3];  // [1024,1024]
  const float* bx = (const float*)d_in[4];  // [1024]
  float* out = (float*)d_out;               // [64,1024]

  char* ws = (char*)d_ws;
  unsigned*       flags = (unsigned*)ws;                      // 8 KB used
  unsigned short* h0    = (unsigned short*)(ws + 65536);      // 128 KB
  unsigned short* h1    = (unsigned short*)(ws + 65536 + 131072);
  float*          xp    = (float*)(ws + (1 << 20));           // 128 MB

  // only flags need zeroing (step 0 reads no h buffer)
  hipMemsetAsync(d_ws, 0, 16384, stream);

  dim3 g1(Bsz * Tsz / 64, Hsz / 64);
  xp_gemm_kernel<<<g1, dim3(256), 0, stream>>>(x, Wx, bx, bh, xp);
  rnn_scan_kernel<<<dim3(128), dim3(128), 0, stream>>>(Wh, xp, out, h0, h1, flags);
}